// Round 2
// baseline (1301.623 us; speedup 1.0000x reference)
//
#include <hip/hip_runtime.h>

// ---------------------------------------------------------------------------
// AttentionModule fused pipeline, MI355X (gfx950).
// B=4, N=4096, K=32, C=128, G=32 (4 ch/group), stats reduce over (4ch, N, K).
//
// Pass plan (all f16 MFMA, fp32 accum, GN folded into following conv weights):
//  K0 prep    : zero stats, convert W_grp/W_fo to f16
//  K1 feat    : f1 = relu(W_feat@feat+b)  (B,64,N) fp32  + gn1 stats g0..15
//  K2 gemm    : x1h = relu(W_grp@gf+b)    (B,64,NK) f16  + gn1 stats g16..31
//  K4 fold    : gn1 -> W1p[b] (f16), b1p[b]
//  K5 u       : u[b,n,co] = W1p_lo @ f1 + b1p   (B,N,128) fp32
//  K6 gemm    : x2 = relu(W1p_hi@x1h + u) (B,128,NK) f16 + gn2 stats
//  K3 gemm    : y3 = W_fo@gfo+b (raw)     (B,128,NK) f16 + gn3 stats
//  K7 folds   : gn2 -> W2p[b],b2p[b];  gn3 -> s3,t3
//  K8a gemm   : scores = W2p@x2+b2p -> mask(count) -> softmax(K) -> wgt f16
//               (wgt aliases x2: each WG reads its p-tile before writing it)
//  K8b final  : out[b,c,n] = sum_k relu(s3*y3+t3)*wgt
//
// R1 change: gemm_k was memory-LATENCY bound (MfmaUtil 2.5 / VALU 3.3 / HBM 13%
// all idle -> ~1 TB/s from ~128B/wave in flight + vmcnt(0) drain at every
// __syncthreads). Now: cross-tile register prefetch (all of next tile's global
// loads issued before the compute phase) + raw s_barrier with manual lgkmcnt
// so prefetched loads stay in flight across barriers.
// R2 change: R1 bench died at container level (no counters; no evidence of a
// kernel fault). Resubmit with rule-#18 hardening: sched_barrier(0) after each
// inline-asm lgkmcnt(0) so the compiler cannot hoist register-only ops past it.
// NOTE: raw barriers require every block to execute the SAME iteration count —
// holds because gridDim.x divides TILES exactly for all instantiations.
// ---------------------------------------------------------------------------

#define B_   4
#define N_   4096
#define KK_  32
#define NK_  131072   // N_*KK_
#define C_   128
#define EPSV 1e-5f

typedef _Float16 hf8 __attribute__((ext_vector_type(8)));
typedef _Float16 hf4 __attribute__((ext_vector_type(4)));
typedef float    f4  __attribute__((ext_vector_type(4)));

// ---------------------------------------------------------------------------
// K0: zero stats (3*256 floats contiguous) + fp32->f16 weight conversion
__global__ void prep_k(const float* __restrict__ Wgrp, const float* __restrict__ Wfo,
                       _Float16* __restrict__ Wgrp_h, _Float16* __restrict__ Wfo_h,
                       float* __restrict__ stats)
{
    int tid = blockIdx.x * 256 + threadIdx.x;
    if (tid < 64 * 128)  Wgrp_h[tid] = (_Float16)Wgrp[tid];
    if (tid < 128 * 128) Wfo_h[tid]  = (_Float16)Wfo[tid];
    if (tid < 768)       stats[tid]  = 0.0f;
}

// ---------------------------------------------------------------------------
// K1: f1 = relu(W_feat @ feat + b_feat), fp32 out (B,64,N); gn1 stats groups 0..15
// (broadcast-along-K multiplicity cancels in the mean -> divisor 4*N at fold)
__global__ void feat_k(const float* __restrict__ feat, const float* __restrict__ Wf,
                       const float* __restrict__ bfeat, float* __restrict__ f1r,
                       float* __restrict__ stats1)
{
    __shared__ float fs[128][64];
    __shared__ float gst[32];
    int tid = threadIdx.x, b = blockIdx.y, n0 = blockIdx.x * 64;
    if (tid < 32) gst[tid] = 0.0f;
    for (int i = tid; i < 128 * 64; i += 256) {
        int ci = i >> 6, n = i & 63;
        fs[ci][n] = feat[((size_t)b * 128 + ci) * N_ + n0 + n];
    }
    __syncthreads();
    int n = tid & 63, cb = (tid >> 6) * 16;
    float gs1[4] = {0,0,0,0}, gs2[4] = {0,0,0,0};
    for (int j = 0; j < 16; j++) {
        int c = cb + j;
        float a = bfeat[c];
        #pragma unroll 16
        for (int ci = 0; ci < 128; ci++) a += Wf[c * 128 + ci] * fs[ci][n];
        a = fmaxf(a, 0.0f);
        f1r[((size_t)b * 64 + c) * N_ + n0 + n] = a;
        gs1[j >> 2] += a; gs2[j >> 2] += a * a;
    }
    for (int g = 0; g < 4; g++) {
        atomicAdd(&gst[((cb >> 2) + g) * 2 + 0], gs1[g]);
        atomicAdd(&gst[((cb >> 2) + g) * 2 + 1], gs2[g]);
    }
    __syncthreads();
    if (tid < 32) atomicAdd(&stats1[b * 64 + tid], gst[tid]);
}

// ---------------------------------------------------------------------------
// fold: stats -> per-channel (s,t); optionally fold into conv weights:
//   Wdst[b][co][c] = f16(Wsrc[co][c]*s[c]);  bdst[b][co] = bsrc[co] + sum_c Wsrc*t
// lowcnt: groups<16 use divisor 4N (f1 path), else 4NK
__global__ void fold_k(const float* __restrict__ stats, const float* __restrict__ gw,
                       const float* __restrict__ gb, const float* __restrict__ Wsrc,
                       const float* __restrict__ bsrc, _Float16* __restrict__ Wdst,
                       float* __restrict__ bdst, float* __restrict__ sdst,
                       float* __restrict__ tdst, int lowcnt)
{
    int b = blockIdx.x, tid = threadIdx.x;
    __shared__ float ss[128], st[128];
    if (tid < 128) {
        int c = tid, g = c >> 2;
        float d  = (lowcnt && g < 16) ? (4.0f * N_) : (4.0f * NK_);
        float S1 = stats[(b * 32 + g) * 2], S2 = stats[(b * 32 + g) * 2 + 1];
        float mu = S1 / d;
        float var = fmaxf(S2 / d - mu * mu, 0.0f);
        float s = gw[c] * rsqrtf(var + EPSV);
        float t = gb[c] - mu * s;
        ss[c] = s; st[c] = t;
        if (sdst) { sdst[b * 128 + c] = s; tdst[b * 128 + c] = t; }
    }
    __syncthreads();
    if (Wdst && tid < 128) {
        int co = tid;
        float a = bsrc[co];
        for (int c = 0; c < 128; c++) {
            float w = Wsrc[co * 128 + c];
            a += w * st[c];
            Wdst[((size_t)b * 128 + co) * 128 + c] = (_Float16)(w * ss[c]);
        }
        bdst[b * 128 + co] = a;
    }
}

// ---------------------------------------------------------------------------
// K5: u[b][n][co] = b1p[co] + sum_{c<64} W1p[b][co][c] * f1[b][c][n]   (fp32)
__global__ void upass_k(const float* __restrict__ f1r, const _Float16* __restrict__ W1p,
                        const float* __restrict__ b1p, float* __restrict__ u)
{
    int b = blockIdx.y, n0 = blockIdx.x * 32, tid = threadIdx.x;
    __shared__ float fs[64][33];
    __shared__ _Float16 wl[128][68];
    for (int i = tid; i < 64 * 32; i += 256) {
        int c = i >> 5, n = i & 31;
        fs[c][n] = f1r[((size_t)b * 64 + c) * N_ + n0 + n];
    }
    for (int i = tid; i < 128 * 64; i += 256) {
        int co = i >> 6, c = i & 63;
        wl[co][c] = W1p[((size_t)b * 128 + co) * 128 + c];
    }
    __syncthreads();
    int co = tid & 127, nh = tid >> 7;
    float bb = b1p[b * 128 + co];
    for (int ps = 0; ps < 16; ps++) {
        int n = nh * 16 + ps;
        float a = bb;
        #pragma unroll 16
        for (int c = 0; c < 64; c++) a += (float)wl[co][c] * fs[c][n];
        u[((size_t)b * N_ + n0 + n) * C_ + co] = a;
    }
}

// ---------------------------------------------------------------------------
// The workhorse GEMM: OUT[co][p] = sum_c W[co][c] * X[c][p]  over position tiles.
// Orientation: MFMA D[p][co] (positions=M). X staged to LDS as xs[p][c] via 4x4
// in-register transpose; W B-frags held in VGPRs for the whole kernel.
// EPI: 0 = relu+store f16+stats, 1 = store raw f16+stats, 2 = mask+softmax(K)+store
//
// Pipeline: registers R hold tile t's global data on loop entry (issued the
// previous iteration). Per iteration:
//   [issue in-iter batch R2 (K2 only)] [B0 raw barrier] [cvt R,R2 -> xs/uld/cld]
//   [issue prefetch R <- tile t+stride] [lgkmcnt(0); sched_barrier; B1 raw barrier]
//   [acc init / MFMA / epilogue]
// Prefetched loads stay in flight across B1 + compute + B0 (no vmcnt(0) drain).
template<int CIN, int COUT, int TP, bool SRCF32, int EPI, bool HASU,
         int WRS, int WCOFF, int COOFF, bool WPB, bool BPB>
__global__ void __launch_bounds__(256, 2) gemm_k(
    const void* srcv, const _Float16* __restrict__ W, const float* __restrict__ bias,
    _Float16* out, float* __restrict__ stats, const float* __restrict__ u,
    const int* __restrict__ cnt)
{
    constexpr int KC  = CIN / 32;
    constexpr int WCO = (COUT == 128) ? 2 : 1;
    constexpr int WP  = 4 / WCO;
    constexpr int TILES = NK_ / TP;
    constexpr int NGR = TP / 32;
    constexpr int TPG = TP / 4;
    constexpr int CQP = 256 / TPG;
    constexpr int PASSES = CIN / (4 * CQP);
    constexpr int PFP = (PASSES > 4) ? 4 : PASSES;   // prefetched passes (VGPR cap)
    constexpr int RIP = PASSES - PFP;                // in-iteration batched passes
    constexpr int NU  = HASU ? (NGR * COUT / 256) : 1;

    __shared__ _Float16 xs[TP][CIN + 8];
    __shared__ float bstat[(EPI != 2) ? COUT * 2 : 1];
    __shared__ float uld[HASU ? NGR * COUT : 1];
    __shared__ int   cld[(EPI == 2) ? NGR : 1];

    const int tid  = threadIdx.x;
    const int lane = tid & 63;
    const int wave = tid >> 6;
    const int l15  = lane & 15;
    const int q    = lane >> 4;
    const int wm   = wave % WP;
    const int wn   = wave / WP;
    const int b    = blockIdx.y;

    // persistent W fragments (B operand): bf[nt][kc] lane holds W[co][c0+q*8+j]
    hf8 bf[4][KC];
    const _Float16* Wb = W + (WPB ? (size_t)b * COUT * WRS : 0);
    #pragma unroll
    for (int nt = 0; nt < 4; nt++) {
        int co = wn * 64 + nt * 16 + l15;
        #pragma unroll
        for (int kc = 0; kc < KC; kc++)
            bf[nt][kc] = *(const hf8*)(Wb + (size_t)co * WRS + WCOFF + kc * 32 + q * 8);
    }
    float biasr[4];
    #pragma unroll
    for (int nt = 0; nt < 4; nt++) {
        int co = wn * 64 + nt * 16 + l15;
        biasr[nt] = bias ? bias[(BPB ? b * COUT : 0) + co] : 0.0f;
    }
    if (EPI != 2) for (int i = tid; i < COUT * 2; i += 256) bstat[i] = 0.0f;

    const int tp = tid % TPG;
    const int cq = tid / TPG;

    // ---- prefetch register state (tile t's global data) ----
    f4  Rf[SRCF32 ? PFP : 1][4];
    hf4 Rh[SRCF32 ? 1 : PFP][4];
    float ur[NU];
    int   cr = 1;

    auto prefetch = [&](int tt) {
        const int pb = tt * TP;
        #pragma unroll
        for (int ps = 0; ps < PFP; ps++) {
            const int c0 = (ps * CQP + cq) * 4;
            #pragma unroll
            for (int r = 0; r < 4; r++) {
                const size_t off = ((size_t)(b * CIN + c0 + r)) * NK_ + pb + tp * 4;
                if constexpr (SRCF32) Rf[ps][r] = *(const f4*)((const float*)srcv + off);
                else                  Rh[ps][r] = *(const hf4*)((const _Float16*)srcv + off);
            }
        }
        if constexpr (HASU) {
            #pragma unroll
            for (int j = 0; j < NU; j++) {
                const int i = j * 256 + tid;
                ur[j] = u[((size_t)b * N_ + (pb >> 5) + i / COUT) * C_ + (i % COUT)];
            }
        }
        if constexpr (EPI == 2) {
            if (tid < NGR) cr = cnt[b * N_ + (pb >> 5) + tid];
        }
    };

    int t = blockIdx.x;
    prefetch(t);

    for (; t < TILES; t += (int)gridDim.x) {
        const int pbase = t * TP;

        // in-iteration batch loads for the non-prefetched passes (K2 only):
        // issue BEFORE B0 so latency overlaps the barrier wait + PFP ds_writes
        f4  R2f[(SRCF32 && RIP > 0) ? RIP : 1][4];
        hf4 R2h[(!SRCF32 && RIP > 0) ? RIP : 1][4];
        if constexpr (RIP > 0) {
            #pragma unroll
            for (int ps = 0; ps < RIP; ps++) {
                const int c0 = ((PFP + ps) * CQP + cq) * 4;
                #pragma unroll
                for (int r = 0; r < 4; r++) {
                    const size_t off = ((size_t)(b * CIN + c0 + r)) * NK_ + pbase + tp * 4;
                    if constexpr (SRCF32) R2f[ps][r] = *(const f4*)((const float*)srcv + off);
                    else                  R2h[ps][r] = *(const hf4*)((const _Float16*)srcv + off);
                }
            }
        }

        // B0: all waves finished READING xs/uld/cld of the previous tile.
        // Raw barrier: no vmcnt drain -> prefetched loads stay in flight.
        asm volatile("" ::: "memory");
        __builtin_amdgcn_s_barrier();
        __builtin_amdgcn_sched_barrier(0);

        // ---- stage prefetched passes into xs (4x4 transpose) ----
        #pragma unroll
        for (int ps = 0; ps < PFP; ps++) {
            const int c0 = (ps * CQP + cq) * 4;
            #pragma unroll
            for (int i = 0; i < 4; i++) {
                hf4 w;
                if constexpr (SRCF32)
                    w = hf4{ (_Float16)Rf[ps][0][i], (_Float16)Rf[ps][1][i],
                             (_Float16)Rf[ps][2][i], (_Float16)Rf[ps][3][i] };
                else
                    w = hf4{ Rh[ps][0][i], Rh[ps][1][i], Rh[ps][2][i], Rh[ps][3][i] };
                *(hf4*)&xs[tp * 4 + i][c0] = w;
            }
        }
        if constexpr (RIP > 0) {
            #pragma unroll
            for (int ps = 0; ps < RIP; ps++) {
                const int c0 = ((PFP + ps) * CQP + cq) * 4;
                #pragma unroll
                for (int i = 0; i < 4; i++) {
                    hf4 w;
                    if constexpr (SRCF32)
                        w = hf4{ (_Float16)R2f[ps][0][i], (_Float16)R2f[ps][1][i],
                                 (_Float16)R2f[ps][2][i], (_Float16)R2f[ps][3][i] };
                    else
                        w = hf4{ R2h[ps][0][i], R2h[ps][1][i], R2h[ps][2][i], R2h[ps][3][i] };
                    *(hf4*)&xs[tp * 4 + i][c0] = w;
                }
            }
        }
        if constexpr (HASU) {
            #pragma unroll
            for (int j = 0; j < NU; j++) uld[j * 256 + tid] = ur[j];
        }
        if constexpr (EPI == 2) {
            if (tid < NGR) cld[tid] = cr < 1 ? 1 : cr;
        }

        // ---- prefetch next tile: loads remain in flight across B1 + compute ----
        const int tn = t + (int)gridDim.x;
        if (tn < TILES) prefetch(tn);

        // B1: xs/uld/cld visible to all waves; only LDS is drained.
        // sched_barrier(0) after the inline waitcnt: rule #18 — stop hipcc from
        // hoisting register-only ops (incl. later ds_read-dependent MFMA) past it.
        asm volatile("s_waitcnt lgkmcnt(0)" ::: "memory");
        __builtin_amdgcn_sched_barrier(0);
        __builtin_amdgcn_s_barrier();
        __builtin_amdgcn_sched_barrier(0);

        // ---- init acc ----
        f4 acc[4][4];
        #pragma unroll
        for (int mt = 0; mt < 4; mt++)
            #pragma unroll
            for (int nt = 0; nt < 4; nt++) {
                float v;
                if (HASU) v = uld[(wm * 2 + (mt >> 1)) * COUT + wn * 64 + nt * 16 + l15];
                else      v = biasr[nt];
                acc[mt][nt] = f4{v, v, v, v};
            }

        // ---- MFMA main loop ----
        #pragma unroll
        for (int kc = 0; kc < KC; kc++) {
            hf8 af[4];
            #pragma unroll
            for (int mt = 0; mt < 4; mt++)
                af[mt] = *(const hf8*)&xs[wm * 64 + mt * 16 + l15][kc * 32 + q * 8];
            #pragma unroll
            for (int mt = 0; mt < 4; mt++)
                #pragma unroll
                for (int nt = 0; nt < 4; nt++)
                    acc[mt][nt] = __builtin_amdgcn_mfma_f32_16x16x32_f16(
                        af[mt], bf[nt][kc], acc[mt][nt], 0, 0, 0);
        }

        // ---- epilogue ----
        if constexpr (EPI != 2) {
            #pragma unroll
            for (int nt = 0; nt < 4; nt++) {
                int co = wn * 64 + nt * 16 + l15;
                float s1 = 0.0f, s2 = 0.0f;
                #pragma unroll
                for (int mt = 0; mt < 4; mt++) {
                    f4 a = acc[mt][nt];
                    #pragma unroll
                    for (int i = 0; i < 4; i++) {
                        if (EPI == 0) a[i] = fmaxf(a[i], 0.0f);
                        s1 += a[i]; s2 += a[i] * a[i];
                    }
                    hf4 hv = { (_Float16)a[0], (_Float16)a[1], (_Float16)a[2], (_Float16)a[3] };
                    *(hf4*)(out + ((size_t)(b * COUT + co)) * NK_ + pbase + wm * 64 + mt * 16 + q * 4) = hv;
                }
                s1 += __shfl_xor(s1, 16); s1 += __shfl_xor(s1, 32);
                s2 += __shfl_xor(s2, 16); s2 += __shfl_xor(s2, 32);
                if (q == 0) {
                    atomicAdd(&bstat[co * 2 + 0], s1);
                    atomicAdd(&bstat[co * 2 + 1], s2);
                }
            }
        } else {
            // masked softmax over k (32 contiguous positions); wave covers 2 n-groups
            #pragma unroll
            for (int nt = 0; nt < 4; nt++) {
                float mx0 = -3e38f, mx1 = -3e38f;
                #pragma unroll
                for (int mt = 0; mt < 4; mt++) {
                    int cv = cld[wm * 2 + (mt >> 1)];
                    #pragma unroll
                    for (int r = 0; r < 4; r++) {
                        int k = (mt & 1) * 16 + q * 4 + r;
                        float v = acc[mt][nt][r];
                        if (k >= cv) v = -1e9f;
                        acc[mt][nt][r] = v;
                        if (mt < 2) mx0 = fmaxf(mx0, v); else mx1 = fmaxf(mx1, v);
                    }
                }
                mx0 = fmaxf(mx0, __shfl_xor(mx0, 16)); mx0 = fmaxf(mx0, __shfl_xor(mx0, 32));
                mx1 = fmaxf(mx1, __shfl_xor(mx1, 16)); mx1 = fmaxf(mx1, __shfl_xor(mx1, 32));
                float sm0 = 0.0f, sm1 = 0.0f;
                #pragma unroll
                for (int mt = 0; mt < 4; mt++) {
                    float m = (mt < 2) ? mx0 : mx1;
                    #pragma unroll
                    for (int r = 0; r < 4; r++) {
                        float e = __expf(acc[mt][nt][r] - m);
                        acc[mt][nt][r] = e;
                        if (mt < 2) sm0 += e; else sm1 += e;
                    }
                }
                sm0 += __shfl_xor(sm0, 16); sm0 += __shfl_xor(sm0, 32);
                sm1 += __shfl_xor(sm1, 16); sm1 += __shfl_xor(sm1, 32);
                float i0 = 1.0f / sm0, i1 = 1.0f / sm1;
                int co = wn * 64 + nt * 16 + l15;
                #pragma unroll
                for (int mt = 0; mt < 4; mt++) {
                    float inv = (mt < 2) ? i0 : i1;
                    hf4 hv = { (_Float16)(acc[mt][nt][0] * inv), (_Float16)(acc[mt][nt][1] * inv),
                               (_Float16)(acc[mt][nt][2] * inv), (_Float16)(acc[mt][nt][3] * inv) };
                    *(hf4*)(out + ((size_t)(b * COUT + co)) * NK_ + pbase + wm * 64 + mt * 16 + q * 4) = hv;
                }
            }
        }
        // no trailing barrier: B0 at the top of the next iteration covers the
        // write(t+1) vs read(t) hazard on xs/uld/cld.
    }

    if constexpr (EPI != 2) {
        // all waves' bstat atomics must land before the flush
        asm volatile("s_waitcnt lgkmcnt(0)" ::: "memory");
        __builtin_amdgcn_sched_barrier(0);
        __builtin_amdgcn_s_barrier();
        __builtin_amdgcn_sched_barrier(0);
        if (stats) {
            for (int i = tid; i < COUT * 2; i += 256) {
                int co = i >> 1, j = i & 1;
                int g = (co + COOFF) >> 2;
                atomicAdd(&stats[(b * 32 + g) * 2 + j], bstat[i]);
            }
        }
    }
}

// ---------------------------------------------------------------------------
// K8b: out[b][c][n] = sum_k relu(s3*y3 + t3) * wgt   (fully coalesced streams)
__global__ void final_k(const _Float16* __restrict__ y3, const _Float16* __restrict__ wgt,
                        const float* __restrict__ s3, const float* __restrict__ t3,
                        float* __restrict__ outp)
{
    int idx = blockIdx.x * 256 + threadIdx.x;   // (b*128+co)*4096 + n
    int bc = idx >> 12;
    float sc = s3[bc], tc = t3[bc];
    const _Float16* yp = y3 + (size_t)idx * 32;
    const _Float16* wp = wgt + (size_t)idx * 32;
    float accv = 0.0f;
    #pragma unroll
    for (int i = 0; i < 4; i++) {
        hf8 yv = *(const hf8*)(yp + i * 8);
        hf8 wv = *(const hf8*)(wp + i * 8);
        #pragma unroll
        for (int j = 0; j < 8; j++) {
            float g = fmaxf(sc * (float)yv[j] + tc, 0.0f);
            accv += g * (float)wv[j];
        }
    }
    outp[idx] = accv;
}

// ---------------------------------------------------------------------------
extern "C" void kernel_launch(void* const* d_in, const int* in_sizes, int n_in,
                              void* d_out, int out_size, void* d_ws, size_t ws_size,
                              hipStream_t stream)
{
    (void)in_sizes; (void)n_in; (void)out_size; (void)ws_size;
    const float* feat   = (const float*)d_in[0];
    const float* gf     = (const float*)d_in[1];
    const float* gfo    = (const float*)d_in[2];
    const int*   count  = (const int*)d_in[3];
    const float* W_feat = (const float*)d_in[4];
    const float* b_feat = (const float*)d_in[5];
    const float* W_grp  = (const float*)d_in[6];
    const float* b_grp  = (const float*)d_in[7];
    const float* gn1w   = (const float*)d_in[8];
    const float* gn1b   = (const float*)d_in[9];
    const float* W_wc1  = (const float*)d_in[10];
    const float* b_wc1  = (const float*)d_in[11];
    const float* gn2w   = (const float*)d_in[12];
    const float* gn2b   = (const float*)d_in[13];
    const float* W_wc2  = (const float*)d_in[14];
    const float* b_wc2  = (const float*)d_in[15];
    const float* W_fo   = (const float*)d_in[16];
    const float* b_fo   = (const float*)d_in[17];
    const float* gn3w   = (const float*)d_in[18];
    const float* gn3b   = (const float*)d_in[19];
    float* out = (float*)d_out;

    char* ws = (char*)d_ws;
    size_t o = 0;
    auto alloc = [&](size_t bytes) { size_t r = o; o += (bytes + 255) & ~(size_t)255; return r; };
    _Float16* x1h    = (_Float16*)(ws + alloc((size_t)64 * B_ * NK_ * 2));   //  67 MB
    _Float16* x2     = (_Float16*)(ws + alloc((size_t)128 * B_ * NK_ * 2));  // 134 MB (wgt aliases)
    _Float16* y3     = (_Float16*)(ws + alloc((size_t)128 * B_ * NK_ * 2));  // 134 MB
    float*    f1r    = (float*)(ws + alloc((size_t)B_ * 64 * N_ * 4));       //   4 MB
    float*    u      = (float*)(ws + alloc((size_t)B_ * N_ * 128 * 4));      //   8 MB
    float*    stats1 = (float*)(ws + alloc(256 * 4));                        // stats1..3 contiguous
    float*    stats2 = (float*)(ws + alloc(256 * 4));
    float*    stats3 = (float*)(ws + alloc(256 * 4));
    _Float16* Wgrp_h = (_Float16*)(ws + alloc(64 * 128 * 2));
    _Float16* Wfo_h  = (_Float16*)(ws + alloc(128 * 128 * 2));
    _Float16* W1p    = (_Float16*)(ws + alloc((size_t)B_ * 128 * 128 * 2));
    float*    b1p    = (float*)(ws + alloc(B_ * 128 * 4));
    _Float16* W2p    = (_Float16*)(ws + alloc((size_t)B_ * 128 * 128 * 2));
    float*    b2p    = (float*)(ws + alloc(B_ * 128 * 4));
    float*    s3     = (float*)(ws + alloc(B_ * 128 * 4));
    float*    t3     = (float*)(ws + alloc(B_ * 128 * 4));
    _Float16* wgt    = x2;  // alias: softmax kernel reads its x2 tile before storing

    prep_k<<<64, 256, 0, stream>>>(W_grp, W_fo, Wgrp_h, Wfo_h, stats1);
    feat_k<<<dim3(64, B_), 256, 0, stream>>>(feat, W_feat, b_feat, f1r, stats1);
    // K2: x1h = relu(W_grp @ gf + b_grp), gn1 stats groups 16..31
    gemm_k<128, 64, 256, true, 0, false, 128, 0, 64, false, false>
        <<<dim3(128, B_), 256, 0, stream>>>(gf, Wgrp_h, b_grp, x1h, stats1, nullptr, nullptr);
    // fold gn1 -> W1p/b1p
    fold_k<<<B_, 256, 0, stream>>>(stats1, gn1w, gn1b, W_wc1, b_wc1, W1p, b1p, nullptr, nullptr, 1);
    upass_k<<<dim3(128, B_), 256, 0, stream>>>(f1r, W1p, b1p, u);
    // K6: x2 = relu(W1p_hi @ x1h + u), gn2 stats
    gemm_k<64, 128, 128, false, 0, true, 128, 64, 0, true, false>
        <<<dim3(256, B_), 256, 0, stream>>>(x1h, W1p, nullptr, x2, stats2, u, nullptr);
    // K3: y3 = W_fo @ gfo + b_fo (raw), gn3 stats
    gemm_k<128, 128, 128, true, 1, false, 128, 0, 0, false, false>
        <<<dim3(256, B_), 256, 0, stream>>>(gfo, Wfo_h, b_fo, y3, stats3, nullptr, nullptr);
    // folds: gn2 -> W2p/b2p ; gn3 -> s3/t3
    fold_k<<<B_, 256, 0, stream>>>(stats2, gn2w, gn2b, W_wc2, b_wc2, W2p, b2p, nullptr, nullptr, 0);
    fold_k<<<B_, 256, 0, stream>>>(stats3, gn3w, gn3b, nullptr, nullptr, nullptr, nullptr, s3, t3, 0);
    // K8a: scores -> mask -> softmax -> wgt (aliases x2)
    gemm_k<128, 128, 128, false, 2, false, 128, 0, 0, true, true>
        <<<dim3(256, B_), 256, 0, stream>>>(x2, W2p, b2p, wgt, nullptr, nullptr, count);
    // K8b: weighted sum
    final_k<<<(B_ * 128 * N_) / 256, 256, 0, stream>>>(y3, wgt, s3, t3, out);
}

// Round 3
// 1014.365 us; speedup vs baseline: 1.2832x; 1.2832x over previous
//
#include <hip/hip_runtime.h>

// ---------------------------------------------------------------------------
// AttentionModule fused pipeline, MI355X (gfx950).
// B=4, N=4096, K=32, C=128, G=32 (4 ch/group), stats reduce over (4ch, N, K).
//
// Pass plan (all f16 MFMA, fp32 accum, GN folded into following conv weights):
//  K0 prep    : zero stats, convert W_grp/W_fo to f16
//  K1 feat    : f1 = relu(W_feat@feat+b)  (B,64,N) fp32  + gn1 stats g0..15
//  K2 gemm    : x1h = relu(W_grp@gf+b)    (B,64,NK) f16  + gn1 stats g16..31
//  K4 fold    : gn1 -> W1p[b] (f16), b1p[b]
//  K5 u       : u[b,n,co] = W1p_lo @ f1 + b1p   (B,N,128) fp32
//  K6 gemm    : x2 = relu(W1p_hi@x1h + u) (B,128,NK) f16 + gn2 stats
//  K3 gemm    : y3 = W_fo@gfo+b (raw)     (B,128,NK) f16 + gn3 stats
//  K7 folds   : gn2 -> W2p[b],b2p[b];  gn3 -> s3,t3
//  K8a gemm   : scores = W2p@x2+b2p -> mask(count) -> softmax(K) -> wgt f16
//               (wgt aliases x2: each WG reads its p-tile before writing it)
//  K8b final  : out[b,c,n] = sum_k relu(s3*y3+t3)*wgt
//
// R2 post-mortem: cross-iteration register prefetch spilled (FETCH +60MB,
// WRITE +43MB scratch traffic; VGPR clamped 128) -> slower. Registers cannot
// live across the whole iteration.
// R3: minimum 2-phase schedule (catalog T3 recipe): LDS double-buffer xs[2][..];
// per iter: [MFMA on buf cur] [commit regs->buf cur^1 (vmcnt via use)]
// [issue loads t+2G] [epilogue stores] [lgkmcnt(0); raw s_barrier].
// Register lifetime = issue..commit only (never across the compute of the
// same data). Stores issued AFTER issue() so vmcnt FIFO waits exclude them.
// One raw barrier/iter (no vmcnt drain). K2 switched TP 256->128 (WP=4) so the
// doubled LDS fits. grid.x=128 -> 8 iters/block, all blocks resident.
// Barrier uniformity: per-block iteration count uniform across its waves.
// ---------------------------------------------------------------------------

#define B_   4
#define N_   4096
#define KK_  32
#define NK_  131072   // N_*KK_
#define C_   128
#define EPSV 1e-5f

typedef _Float16 hf8 __attribute__((ext_vector_type(8)));
typedef _Float16 hf4 __attribute__((ext_vector_type(4)));
typedef float    f4  __attribute__((ext_vector_type(4)));

// ---------------------------------------------------------------------------
// K0: zero stats (3*256 floats contiguous) + fp32->f16 weight conversion
__global__ void prep_k(const float* __restrict__ Wgrp, const float* __restrict__ Wfo,
                       _Float16* __restrict__ Wgrp_h, _Float16* __restrict__ Wfo_h,
                       float* __restrict__ stats)
{
    int tid = blockIdx.x * 256 + threadIdx.x;
    if (tid < 64 * 128)  Wgrp_h[tid] = (_Float16)Wgrp[tid];
    if (tid < 128 * 128) Wfo_h[tid]  = (_Float16)Wfo[tid];
    if (tid < 768)       stats[tid]  = 0.0f;
}

// ---------------------------------------------------------------------------
// K1: f1 = relu(W_feat @ feat + b_feat), fp32 out (B,64,N); gn1 stats groups 0..15
__global__ void feat_k(const float* __restrict__ feat, const float* __restrict__ Wf,
                       const float* __restrict__ bfeat, float* __restrict__ f1r,
                       float* __restrict__ stats1)
{
    __shared__ float fs[128][64];
    __shared__ float gst[32];
    int tid = threadIdx.x, b = blockIdx.y, n0 = blockIdx.x * 64;
    if (tid < 32) gst[tid] = 0.0f;
    for (int i = tid; i < 128 * 64; i += 256) {
        int ci = i >> 6, n = i & 63;
        fs[ci][n] = feat[((size_t)b * 128 + ci) * N_ + n0 + n];
    }
    __syncthreads();
    int n = tid & 63, cb = (tid >> 6) * 16;
    float gs1[4] = {0,0,0,0}, gs2[4] = {0,0,0,0};
    for (int j = 0; j < 16; j++) {
        int c = cb + j;
        float a = bfeat[c];
        #pragma unroll 16
        for (int ci = 0; ci < 128; ci++) a += Wf[c * 128 + ci] * fs[ci][n];
        a = fmaxf(a, 0.0f);
        f1r[((size_t)b * 64 + c) * N_ + n0 + n] = a;
        gs1[j >> 2] += a; gs2[j >> 2] += a * a;
    }
    for (int g = 0; g < 4; g++) {
        atomicAdd(&gst[((cb >> 2) + g) * 2 + 0], gs1[g]);
        atomicAdd(&gst[((cb >> 2) + g) * 2 + 1], gs2[g]);
    }
    __syncthreads();
    if (tid < 32) atomicAdd(&stats1[b * 64 + tid], gst[tid]);
}

// ---------------------------------------------------------------------------
// fold: stats -> per-channel (s,t); optionally fold into conv weights
__global__ void fold_k(const float* __restrict__ stats, const float* __restrict__ gw,
                       const float* __restrict__ gb, const float* __restrict__ Wsrc,
                       const float* __restrict__ bsrc, _Float16* __restrict__ Wdst,
                       float* __restrict__ bdst, float* __restrict__ sdst,
                       float* __restrict__ tdst, int lowcnt)
{
    int b = blockIdx.x, tid = threadIdx.x;
    __shared__ float ss[128], st[128];
    if (tid < 128) {
        int c = tid, g = c >> 2;
        float d  = (lowcnt && g < 16) ? (4.0f * N_) : (4.0f * NK_);
        float S1 = stats[(b * 32 + g) * 2], S2 = stats[(b * 32 + g) * 2 + 1];
        float mu = S1 / d;
        float var = fmaxf(S2 / d - mu * mu, 0.0f);
        float s = gw[c] * rsqrtf(var + EPSV);
        float t = gb[c] - mu * s;
        ss[c] = s; st[c] = t;
        if (sdst) { sdst[b * 128 + c] = s; tdst[b * 128 + c] = t; }
    }
    __syncthreads();
    if (Wdst && tid < 128) {
        int co = tid;
        float a = bsrc[co];
        for (int c = 0; c < 128; c++) {
            float w = Wsrc[co * 128 + c];
            a += w * st[c];
            Wdst[((size_t)b * 128 + co) * 128 + c] = (_Float16)(w * ss[c]);
        }
        bdst[b * 128 + co] = a;
    }
}

// ---------------------------------------------------------------------------
// K5: u[b][n][co] = b1p[co] + sum_{c<64} W1p[b][co][c] * f1[b][c][n]   (fp32)
__global__ void upass_k(const float* __restrict__ f1r, const _Float16* __restrict__ W1p,
                        const float* __restrict__ b1p, float* __restrict__ u)
{
    int b = blockIdx.y, n0 = blockIdx.x * 32, tid = threadIdx.x;
    __shared__ float fs[64][33];
    __shared__ _Float16 wl[128][68];
    for (int i = tid; i < 64 * 32; i += 256) {
        int c = i >> 5, n = i & 31;
        fs[c][n] = f1r[((size_t)b * 64 + c) * N_ + n0 + n];
    }
    for (int i = tid; i < 128 * 64; i += 256) {
        int co = i >> 6, c = i & 63;
        wl[co][c] = W1p[((size_t)b * 128 + co) * 128 + c];
    }
    __syncthreads();
    int co = tid & 127, nh = tid >> 7;
    float bb = b1p[b * 128 + co];
    for (int ps = 0; ps < 16; ps++) {
        int n = nh * 16 + ps;
        float a = bb;
        #pragma unroll 16
        for (int c = 0; c < 64; c++) a += (float)wl[co][c] * fs[c][n];
        u[((size_t)b * N_ + n0 + n) * C_ + co] = a;
    }
}

// ---------------------------------------------------------------------------
// Workhorse GEMM, 2-phase double-buffered.
// OUT[co][p] = sum_c W[co][c] * X[c][p] over position tiles; D[p][co] (p=M).
// WP = waves along positions (4/WP waves along co). MT = TP/(16*WP) row-tiles,
// NT = COUT/(16*(4/WP)) co-tiles per wave.
// EPI: 0 relu+store+stats, 1 raw store+stats, 2 mask+softmax(K)+store.
template<int CIN, int COUT, int TP, bool SRCF32, int EPI, bool HASU,
         int WRS, int WCOFF, int COOFF, bool WPB, bool BPB, int WP>
__global__ void __launch_bounds__(256, 2) gemm_k(
    const void* srcv, const _Float16* __restrict__ W, const float* __restrict__ bias,
    _Float16* out, float* __restrict__ stats, const float* __restrict__ u,
    const int* __restrict__ cnt)
{
    constexpr int KC  = CIN / 32;
    constexpr int WCO = 4 / WP;
    constexpr int MT  = TP / (16 * WP);
    constexpr int NT  = COUT / (16 * WCO);
    constexpr int TILES = NK_ / TP;
    constexpr int NGR = TP / 32;
    constexpr int TPG = TP / 4;
    constexpr int CQP = 256 / TPG;
    constexpr int PASSES = CIN / (4 * CQP);
    constexpr int NU  = HASU ? (NGR * COUT / 256) : 1;

    __shared__ _Float16 xs[2][TP][CIN + 8];
    __shared__ float bstat[(EPI != 2) ? COUT * 2 : 1];
    __shared__ float uld[HASU ? 2 : 1][HASU ? NGR * COUT : 1];
    __shared__ int   cld[2][(EPI == 2) ? NGR : 1];

    const int tid  = threadIdx.x;
    const int lane = tid & 63;
    const int wave = tid >> 6;
    const int l15  = lane & 15;
    const int q    = lane >> 4;
    const int wm   = wave % WP;
    const int wn   = wave / WP;
    const int pw   = wm * (16 * MT);
    const int b    = blockIdx.y;

    // persistent W fragments (B operand)
    hf8 bf[NT][KC];
    const _Float16* Wb = W + (WPB ? (size_t)b * COUT * WRS : 0);
    #pragma unroll
    for (int nt = 0; nt < NT; nt++) {
        int co = wn * (16 * NT) + nt * 16 + l15;
        #pragma unroll
        for (int kc = 0; kc < KC; kc++)
            bf[nt][kc] = *(const hf8*)(Wb + (size_t)co * WRS + WCOFF + kc * 32 + q * 8);
    }
    float biasr[NT];
    #pragma unroll
    for (int nt = 0; nt < NT; nt++) {
        int co = wn * (16 * NT) + nt * 16 + l15;
        biasr[nt] = bias ? bias[(BPB ? b * COUT : 0) + co] : 0.0f;
    }
    if (EPI != 2) for (int i = tid; i < COUT * 2; i += 256) bstat[i] = 0.0f;

    const int tp = tid % TPG;
    const int cq = tid / TPG;

    // ---- in-flight register state: lifetime = issue() .. commit() only ----
    f4  Rf[SRCF32 ? PASSES : 1][4];
    hf4 Rh[SRCF32 ? 1 : PASSES][4];
    float ur[NU];
    int   cr = 1;

    auto issue = [&](int tt) {   // pure loads, no waits
        const int pb = tt * TP;
        #pragma unroll
        for (int ps = 0; ps < PASSES; ps++) {
            const int c0 = (ps * CQP + cq) * 4;
            #pragma unroll
            for (int r = 0; r < 4; r++) {
                const size_t off = ((size_t)(b * CIN + c0 + r)) * NK_ + pb + tp * 4;
                if constexpr (SRCF32) Rf[ps][r] = *(const f4*)((const float*)srcv + off);
                else                  Rh[ps][r] = *(const hf4*)((const _Float16*)srcv + off);
            }
        }
        if constexpr (HASU) {
            #pragma unroll
            for (int j = 0; j < NU; j++) {
                const int i = j * 256 + tid;
                ur[j] = u[((size_t)b * N_ + (pb >> 5) + i / COUT) * C_ + (i % COUT)];
            }
        }
        if constexpr (EPI == 2) {
            if (tid < NGR) cr = cnt[b * N_ + (pb >> 5) + tid];
        }
    };

    auto commit = [&](int nb) {  // cvt + ds_write (compiler inserts vmcnt waits)
        #pragma unroll
        for (int ps = 0; ps < PASSES; ps++) {
            const int c0 = (ps * CQP + cq) * 4;
            #pragma unroll
            for (int i = 0; i < 4; i++) {
                hf4 w;
                if constexpr (SRCF32)
                    w = hf4{ (_Float16)Rf[ps][0][i], (_Float16)Rf[ps][1][i],
                             (_Float16)Rf[ps][2][i], (_Float16)Rf[ps][3][i] };
                else
                    w = hf4{ Rh[ps][0][i], Rh[ps][1][i], Rh[ps][2][i], Rh[ps][3][i] };
                *(hf4*)&xs[nb][tp * 4 + i][c0] = w;
            }
        }
        if constexpr (HASU) {
            #pragma unroll
            for (int j = 0; j < NU; j++) uld[nb][j * 256 + tid] = ur[j];
        }
        if constexpr (EPI == 2) {
            if (tid < NGR) cld[nb][tid] = cr < 1 ? 1 : cr;
        }
    };

    const int t0 = blockIdx.x;
    const int G  = (int)gridDim.x;

    // ---- prologue: fill buf0, start loads for buf1 ----
    issue(t0);
    commit(0);
    if (t0 + G < TILES) issue(t0 + G);
    asm volatile("s_waitcnt lgkmcnt(0)" ::: "memory");
    __builtin_amdgcn_sched_barrier(0);
    __builtin_amdgcn_s_barrier();
    __builtin_amdgcn_sched_barrier(0);

    int it = 0;
    for (int t = t0; t < TILES; t += G, ++it) {
        const int cur = it & 1;
        const int pbase = t * TP;

        // ---- init acc ----
        f4 acc[MT][NT];
        #pragma unroll
        for (int mt = 0; mt < MT; mt++)
            #pragma unroll
            for (int nt = 0; nt < NT; nt++) {
                float v;
                if (HASU) v = uld[cur][(wm * 2 + (mt >> 1)) * COUT + wn * (16 * NT) + nt * 16 + l15];
                else      v = biasr[nt];
                acc[mt][nt] = f4{v, v, v, v};
            }

        // ---- MFMA on buf[cur] (overlaps residual latency of in-flight loads) ----
        #pragma unroll
        for (int kc = 0; kc < KC; kc++) {
            hf8 af[MT];
            #pragma unroll
            for (int mt = 0; mt < MT; mt++)
                af[mt] = *(const hf8*)&xs[cur][pw + mt * 16 + l15][kc * 32 + q * 8];
            #pragma unroll
            for (int mt = 0; mt < MT; mt++)
                #pragma unroll
                for (int nt = 0; nt < NT; nt++)
                    acc[mt][nt] = __builtin_amdgcn_mfma_f32_16x16x32_f16(
                        af[mt], bf[nt][kc], acc[mt][nt], 0, 0, 0);
        }

        // ---- stage next tile into buf[cur^1]; then start loads for t+2G ----
        if (t + G < TILES) {
            commit(cur ^ 1);
            if (t + 2 * G < TILES) issue(t + 2 * G);
        }

        // ---- epilogue (stores issued AFTER issue(): vmcnt FIFO excludes them) ----
        if constexpr (EPI != 2) {
            #pragma unroll
            for (int nt = 0; nt < NT; nt++) {
                int co = wn * (16 * NT) + nt * 16 + l15;
                float s1 = 0.0f, s2 = 0.0f;
                #pragma unroll
                for (int mt = 0; mt < MT; mt++) {
                    f4 a = acc[mt][nt];
                    #pragma unroll
                    for (int i = 0; i < 4; i++) {
                        if (EPI == 0) a[i] = fmaxf(a[i], 0.0f);
                        s1 += a[i]; s2 += a[i] * a[i];
                    }
                    hf4 hv = { (_Float16)a[0], (_Float16)a[1], (_Float16)a[2], (_Float16)a[3] };
                    *(hf4*)(out + ((size_t)(b * COUT + co)) * NK_ + pbase + pw + mt * 16 + q * 4) = hv;
                }
                s1 += __shfl_xor(s1, 16); s1 += __shfl_xor(s1, 32);
                s2 += __shfl_xor(s2, 16); s2 += __shfl_xor(s2, 32);
                if (q == 0) {
                    atomicAdd(&bstat[co * 2 + 0], s1);
                    atomicAdd(&bstat[co * 2 + 1], s2);
                }
            }
        } else {
            // masked softmax over k; MT==4 here (WP=2), wave covers 2 n-groups
            #pragma unroll
            for (int nt = 0; nt < NT; nt++) {
                float mx0 = -3e38f, mx1 = -3e38f;
                #pragma unroll
                for (int mt = 0; mt < MT; mt++) {
                    int cv = cld[cur][wm * 2 + (mt >> 1)];
                    #pragma unroll
                    for (int r = 0; r < 4; r++) {
                        int k = (mt & 1) * 16 + q * 4 + r;
                        float v = acc[mt][nt][r];
                        if (k >= cv) v = -1e9f;
                        acc[mt][nt][r] = v;
                        if (mt < 2) mx0 = fmaxf(mx0, v); else mx1 = fmaxf(mx1, v);
                    }
                }
                mx0 = fmaxf(mx0, __shfl_xor(mx0, 16)); mx0 = fmaxf(mx0, __shfl_xor(mx0, 32));
                mx1 = fmaxf(mx1, __shfl_xor(mx1, 16)); mx1 = fmaxf(mx1, __shfl_xor(mx1, 32));
                float sm0 = 0.0f, sm1 = 0.0f;
                #pragma unroll
                for (int mt = 0; mt < MT; mt++) {
                    float m = (mt < 2) ? mx0 : mx1;
                    #pragma unroll
                    for (int r = 0; r < 4; r++) {
                        float e = __expf(acc[mt][nt][r] - m);
                        acc[mt][nt][r] = e;
                        if (mt < 2) sm0 += e; else sm1 += e;
                    }
                }
                sm0 += __shfl_xor(sm0, 16); sm0 += __shfl_xor(sm0, 32);
                sm1 += __shfl_xor(sm1, 16); sm1 += __shfl_xor(sm1, 32);
                float i0 = 1.0f / sm0, i1 = 1.0f / sm1;
                int co = wn * (16 * NT) + nt * 16 + l15;
                #pragma unroll
                for (int mt = 0; mt < MT; mt++) {
                    float inv = (mt < 2) ? i0 : i1;
                    hf4 hv = { (_Float16)(acc[mt][nt][0] * inv), (_Float16)(acc[mt][nt][1] * inv),
                               (_Float16)(acc[mt][nt][2] * inv), (_Float16)(acc[mt][nt][3] * inv) };
                    *(hf4*)(out + ((size_t)(b * COUT + co)) * NK_ + pbase + pw + mt * 16 + q * 4) = hv;
                }
            }
        }

        // single per-iter barrier: buf[cur^1] ds_writes visible; reads of
        // buf[cur] are consumed above. Raw barrier: no vmcnt drain.
        asm volatile("s_waitcnt lgkmcnt(0)" ::: "memory");
        __builtin_amdgcn_sched_barrier(0);
        __builtin_amdgcn_s_barrier();
        __builtin_amdgcn_sched_barrier(0);
    }

    if constexpr (EPI != 2) {
        if (stats) {
            for (int i = tid; i < COUT * 2; i += 256) {
                int co = i >> 1, j = i & 1;
                int g = (co + COOFF) >> 2;
                atomicAdd(&stats[(b * 32 + g) * 2 + j], bstat[i]);
            }
        }
    }
}

// ---------------------------------------------------------------------------
// K8b: out[b][c][n] = sum_k relu(s3*y3 + t3) * wgt
__global__ void final_k(const _Float16* __restrict__ y3, const _Float16* __restrict__ wgt,
                        const float* __restrict__ s3, const float* __restrict__ t3,
                        float* __restrict__ outp)
{
    int idx = blockIdx.x * 256 + threadIdx.x;   // (b*128+co)*4096 + n
    int bc = idx >> 12;
    float sc = s3[bc], tc = t3[bc];
    const _Float16* yp = y3 + (size_t)idx * 32;
    const _Float16* wp = wgt + (size_t)idx * 32;
    float accv = 0.0f;
    #pragma unroll
    for (int i = 0; i < 4; i++) {
        hf8 yv = *(const hf8*)(yp + i * 8);
        hf8 wv = *(const hf8*)(wp + i * 8);
        #pragma unroll
        for (int j = 0; j < 8; j++) {
            float g = fmaxf(sc * (float)yv[j] + tc, 0.0f);
            accv += g * (float)wv[j];
        }
    }
    outp[idx] = accv;
}

// ---------------------------------------------------------------------------
extern "C" void kernel_launch(void* const* d_in, const int* in_sizes, int n_in,
                              void* d_out, int out_size, void* d_ws, size_t ws_size,
                              hipStream_t stream)
{
    (void)in_sizes; (void)n_in; (void)out_size; (void)ws_size;
    const float* feat   = (const float*)d_in[0];
    const float* gf     = (const float*)d_in[1];
    const float* gfo    = (const float*)d_in[2];
    const int*   count  = (const int*)d_in[3];
    const float* W_feat = (const float*)d_in[4];
    const float* b_feat = (const float*)d_in[5];
    const float* W_grp  = (const float*)d_in[6];
    const float* b_grp  = (const float*)d_in[7];
    const float* gn1w   = (const float*)d_in[8];
    const float* gn1b   = (const float*)d_in[9];
    const float* W_wc1  = (const float*)d_in[10];
    const float* b_wc1  = (const float*)d_in[11];
    const float* gn2w   = (const float*)d_in[12];
    const float* gn2b   = (const float*)d_in[13];
    const float* W_wc2  = (const float*)d_in[14];
    const float* b_wc2  = (const float*)d_in[15];
    const float* W_fo   = (const float*)d_in[16];
    const float* b_fo   = (const float*)d_in[17];
    const float* gn3w   = (const float*)d_in[18];
    const float* gn3b   = (const float*)d_in[19];
    float* out = (float*)d_out;

    char* ws = (char*)d_ws;
    size_t o = 0;
    auto alloc = [&](size_t bytes) { size_t r = o; o += (bytes + 255) & ~(size_t)255; return r; };
    _Float16* x1h    = (_Float16*)(ws + alloc((size_t)64 * B_ * NK_ * 2));   //  67 MB
    _Float16* x2     = (_Float16*)(ws + alloc((size_t)128 * B_ * NK_ * 2));  // 134 MB (wgt aliases)
    _Float16* y3     = (_Float16*)(ws + alloc((size_t)128 * B_ * NK_ * 2));  // 134 MB
    float*    f1r    = (float*)(ws + alloc((size_t)B_ * 64 * N_ * 4));       //   4 MB
    float*    u      = (float*)(ws + alloc((size_t)B_ * N_ * 128 * 4));      //   8 MB
    float*    stats1 = (float*)(ws + alloc(256 * 4));                        // stats1..3 contiguous
    float*    stats2 = (float*)(ws + alloc(256 * 4));
    float*    stats3 = (float*)(ws + alloc(256 * 4));
    _Float16* Wgrp_h = (_Float16*)(ws + alloc(64 * 128 * 2));
    _Float16* Wfo_h  = (_Float16*)(ws + alloc(128 * 128 * 2));
    _Float16* W1p    = (_Float16*)(ws + alloc((size_t)B_ * 128 * 128 * 2));
    float*    b1p    = (float*)(ws + alloc(B_ * 128 * 4));
    _Float16* W2p    = (_Float16*)(ws + alloc((size_t)B_ * 128 * 128 * 2));
    float*    b2p    = (float*)(ws + alloc(B_ * 128 * 4));
    float*    s3     = (float*)(ws + alloc(B_ * 128 * 4));
    float*    t3     = (float*)(ws + alloc(B_ * 128 * 4));
    _Float16* wgt    = x2;  // alias: each tile is read (staged) before its write

    prep_k<<<64, 256, 0, stream>>>(W_grp, W_fo, Wgrp_h, Wfo_h, stats1);
    feat_k<<<dim3(64, B_), 256, 0, stream>>>(feat, W_feat, b_feat, f1r, stats1);
    // K2: x1h = relu(W_grp @ gf + b_grp), gn1 stats groups 16..31  (WP=4)
    gemm_k<128, 64, 128, true, 0, false, 128, 0, 64, false, false, 4>
        <<<dim3(128, B_), 256, 0, stream>>>(gf, Wgrp_h, b_grp, x1h, stats1, nullptr, nullptr);
    // fold gn1 -> W1p/b1p
    fold_k<<<B_, 256, 0, stream>>>(stats1, gn1w, gn1b, W_wc1, b_wc1, W1p, b1p, nullptr, nullptr, 1);
    upass_k<<<dim3(128, B_), 256, 0, stream>>>(f1r, W1p, b1p, u);
    // K6: x2 = relu(W1p_hi @ x1h + u), gn2 stats
    gemm_k<64, 128, 128, false, 0, true, 128, 64, 0, true, false, 2>
        <<<dim3(128, B_), 256, 0, stream>>>(x1h, W1p, nullptr, x2, stats2, u, nullptr);
    // K3: y3 = W_fo @ gfo + b_fo (raw), gn3 stats
    gemm_k<128, 128, 128, true, 1, false, 128, 0, 0, false, false, 2>
        <<<dim3(128, B_), 256, 0, stream>>>(gfo, Wfo_h, b_fo, y3, stats3, nullptr, nullptr);
    // folds: gn2 -> W2p/b2p ; gn3 -> s3/t3
    fold_k<<<B_, 256, 0, stream>>>(stats2, gn2w, gn2b, W_wc2, b_wc2, W2p, b2p, nullptr, nullptr, 0);
    fold_k<<<B_, 256, 0, stream>>>(stats3, gn3w, gn3b, nullptr, nullptr, nullptr, nullptr, s3, t3, 0);
    // K8a: scores -> mask -> softmax -> wgt (aliases x2)
    gemm_k<128, 128, 128, false, 2, false, 128, 0, 0, true, true, 2>
        <<<dim3(128, B_), 256, 0, stream>>>(x2, W2p, b2p, wgt, nullptr, nullptr, count);
    // K8b: weighted sum
    final_k<<<(B_ * 128 * N_) / 256, 256, 0, stream>>>(y3, wgt, s3, t3, out);
}